// Round 1
// baseline (388.166 us; speedup 1.0000x reference)
//
#include <hip/hip_runtime.h>
#include <math.h>

// AccumulateNeighbours meanmax: out[v] = [mean_k feat[nidx[v,k]], max_k feat[nidx[v,k]]]
// V=150000, K=32, F=96. feat fp32 [V,F], nidx int32 [V,K], out fp32 [V,2F].

constexpr int V  = 150000;
constexpr int K  = 32;
constexpr int F  = 96;
constexpr int C  = F / 4;        // 24 float4 chunks per vertex row
constexpr int VB = 8;            // vertices per block
constexpr int BLOCK = VB * C;    // 192 threads = 3 waves

__global__ __launch_bounds__(BLOCK)
void accum_meanmax_kernel(const float4* __restrict__ feat4,   // [V, C]
                          const int*    __restrict__ nidx,    // [V, K]
                          float4*       __restrict__ out4)    // [V, 2*C]
{
    __shared__ int sidx[VB * K];   // 256 indices, 1 KiB

    const int tid   = threadIdx.x;
    const int vbase = blockIdx.x * VB;

    // Stage this block's neighbor indices into LDS (coalesced).
    for (int i = tid; i < VB * K; i += BLOCK) {
        sidx[i] = nidx[vbase * K + i];
    }
    __syncthreads();

    const int vl = tid / C;        // local vertex [0,8)
    const int c  = tid % C;        // float4 chunk [0,24)
    const int v  = vbase + vl;
    if (v >= V) return;            // grid is exact (150000/8), kept for safety

    float4 s = make_float4(0.f, 0.f, 0.f, 0.f);
    float4 m = make_float4(-INFINITY, -INFINITY, -INFINITY, -INFINITY);

    const int* my_idx = &sidx[vl * K];

    #pragma unroll 8
    for (int k = 0; k < K; ++k) {
        const int n = my_idx[k];                 // LDS broadcast across the 24 lanes of this vertex
        const float4 x = feat4[n * C + c];       // 16B gather; 24 lanes cover the full 384B row
        s.x += x.x; s.y += x.y; s.z += x.z; s.w += x.w;
        m.x = fmaxf(m.x, x.x);
        m.y = fmaxf(m.y, x.y);
        m.z = fmaxf(m.z, x.z);
        m.w = fmaxf(m.w, x.w);
    }

    const float inv = 1.0f / (float)K;
    float4 mean = make_float4(s.x * inv, s.y * inv, s.z * inv, s.w * inv);

    // out row: [mean(0..95), max(0..95)] -> 2*C float4 per vertex
    out4[v * (2 * C) + c]     = mean;
    out4[v * (2 * C) + C + c] = m;
}

extern "C" void kernel_launch(void* const* d_in, const int* in_sizes, int n_in,
                              void* d_out, int out_size, void* d_ws, size_t ws_size,
                              hipStream_t stream) {
    const float4* feat4 = (const float4*)d_in[0];
    const int*    nidx  = (const int*)d_in[1];
    float4*       out4  = (float4*)d_out;

    const int grid = (V + VB - 1) / VB;   // 18750
    accum_meanmax_kernel<<<grid, BLOCK, 0, stream>>>(feat4, nidx, out4);
}

// Round 2
// 311.782 us; speedup vs baseline: 1.2450x; 1.2450x over previous
//
#include <hip/hip_runtime.h>
#include <hip/hip_fp16.h>
#include <math.h>

// AccumulateNeighbours meanmax: out[v] = [mean_k feat[nidx[v,k]], max_k feat[nidx[v,k]]]
// V=150000, K=32, F=96. feat fp32 [V,F], nidx int32 [V,K], out fp32 [V,2F].
//
// Strategy: the gather is bound by the L2-miss (fabric/L3) path (R1: FETCH=849MB
// @ ~3.2TB/s, VALUBusy 8.8%). Halve gathered bytes by pre-converting feat to fp16
// in d_ws, then gather 192B fp16 rows. Accumulate fp32. absmax ~2.6e-3 << 0.104.

constexpr int V = 150000;
constexpr int K = 32;
constexpr int F = 96;

// ---------------- fp16 path ----------------
constexpr int C2    = F / 8;       // 12 x 16B chunks per fp16 row (192 B)
constexpr int VB2   = 16;          // vertices per block
constexpr int BLK2  = VB2 * C2;    // 192 threads

__global__ void f32_to_f16(const float4* __restrict__ in, __half2* __restrict__ out, int n4) {
    int i = blockIdx.x * blockDim.x + threadIdx.x;
    if (i < n4) {
        float4 x = in[i];
        out[2 * i]     = __floats2half2_rn(x.x, x.y);
        out[2 * i + 1] = __floats2half2_rn(x.z, x.w);
    }
}

__global__ __launch_bounds__(BLK2)
void accum_meanmax_f16(const uint4* __restrict__ feat_h,  // [V, C2] 16B chunks of halfs
                       const int*   __restrict__ nidx,    // [V, K]
                       float4*      __restrict__ out4)    // [V, 2*F/4] = [V,48]
{
    __shared__ int sidx[VB2 * K];   // 512 indices, 2 KiB

    const int tid   = threadIdx.x;
    const int vbase = blockIdx.x * VB2;

    for (int i = tid; i < VB2 * K; i += BLK2)
        sidx[i] = nidx[vbase * K + i];
    __syncthreads();

    const int vl = tid / C2;        // local vertex [0,16)
    const int c  = tid % C2;        // 16B chunk   [0,12)
    const int v  = vbase + vl;

    float s[8], m[8];
    #pragma unroll
    for (int j = 0; j < 8; ++j) { s[j] = 0.f; m[j] = -INFINITY; }

    const int* my_idx = &sidx[vl * K];

    #pragma unroll 8
    for (int k = 0; k < K; ++k) {
        const int n = my_idx[k];                 // LDS broadcast (12 lanes same addr)
        const uint4 raw = feat_h[n * C2 + c];    // 16B gather = 8 halfs
        const unsigned u[4] = { raw.x, raw.y, raw.z, raw.w };
        #pragma unroll
        for (int j = 0; j < 4; ++j) {
            const __half2 h = *reinterpret_cast<const __half2*>(&u[j]);
            const float2 f = __half22float2(h);
            s[2 * j]     += f.x;
            s[2 * j + 1] += f.y;
            m[2 * j]     = fmaxf(m[2 * j],     f.x);
            m[2 * j + 1] = fmaxf(m[2 * j + 1], f.y);
        }
    }

    const float inv = 1.0f / (float)K;
    // thread covers features [8c, 8c+8) -> float4 chunks 2c, 2c+1 of each half-row
    float4 mn0 = make_float4(s[0] * inv, s[1] * inv, s[2] * inv, s[3] * inv);
    float4 mn1 = make_float4(s[4] * inv, s[5] * inv, s[6] * inv, s[7] * inv);
    float4 mx0 = make_float4(m[0], m[1], m[2], m[3]);
    float4 mx1 = make_float4(m[4], m[5], m[6], m[7]);

    const int row = v * (2 * F / 4);             // 48 float4 per out row
    out4[row + 2 * c]              = mn0;
    out4[row + 2 * c + 1]          = mn1;
    out4[row + F / 4 + 2 * c]      = mx0;
    out4[row + F / 4 + 2 * c + 1]  = mx1;
}

// ---------------- fp32 fallback (R1 kernel) ----------------
constexpr int C  = F / 4;
constexpr int VB = 8;
constexpr int BLK = VB * C;

__global__ __launch_bounds__(BLK)
void accum_meanmax_f32(const float4* __restrict__ feat4,
                       const int*    __restrict__ nidx,
                       float4*       __restrict__ out4)
{
    __shared__ int sidx[VB * K];
    const int tid   = threadIdx.x;
    const int vbase = blockIdx.x * VB;
    for (int i = tid; i < VB * K; i += BLK)
        sidx[i] = nidx[vbase * K + i];
    __syncthreads();

    const int vl = tid / C;
    const int c  = tid % C;
    const int v  = vbase + vl;

    float4 s = make_float4(0.f, 0.f, 0.f, 0.f);
    float4 m = make_float4(-INFINITY, -INFINITY, -INFINITY, -INFINITY);
    const int* my_idx = &sidx[vl * K];

    #pragma unroll 8
    for (int k = 0; k < K; ++k) {
        const int n = my_idx[k];
        const float4 x = feat4[n * C + c];
        s.x += x.x; s.y += x.y; s.z += x.z; s.w += x.w;
        m.x = fmaxf(m.x, x.x); m.y = fmaxf(m.y, x.y);
        m.z = fmaxf(m.z, x.z); m.w = fmaxf(m.w, x.w);
    }
    const float inv = 1.0f / (float)K;
    out4[v * (2 * C) + c]     = make_float4(s.x * inv, s.y * inv, s.z * inv, s.w * inv);
    out4[v * (2 * C) + C + c] = m;
}

extern "C" void kernel_launch(void* const* d_in, const int* in_sizes, int n_in,
                              void* d_out, int out_size, void* d_ws, size_t ws_size,
                              hipStream_t stream) {
    const float* feat = (const float*)d_in[0];
    const int*   nidx = (const int*)d_in[1];
    float4*      out4 = (float4*)d_out;

    const size_t need = (size_t)V * F * sizeof(__half);   // 28.8 MB

    if (ws_size >= need) {
        __half2* feat_h = (__half2*)d_ws;
        const int n4 = V * F / 4;                          // 3,600,000
        f32_to_f16<<<(n4 + 255) / 256, 256, 0, stream>>>((const float4*)feat, feat_h, n4);
        accum_meanmax_f16<<<V / VB2, BLK2, 0, stream>>>((const uint4*)feat_h, nidx, out4);
    } else {
        accum_meanmax_f32<<<V / VB, BLK, 0, stream>>>((const float4*)feat, nidx, out4);
    }
}